// Round 12
// baseline (1731.736 us; speedup 1.0000x reference)
//
#include <hip/hip_runtime.h>

typedef unsigned short u16;
typedef _Float16 f16;
typedef _Float16 fh8 __attribute__((ext_vector_type(8)));
typedef float f32x4 __attribute__((ext_vector_type(4)));

#define cD   1024
#define cN   2048
#define cH   8
#define cDK  128
#define cDFF 4096
#define cL   4
#define LAM_ 0.08838834764831845f  /* 1/sqrt(128) */

__device__ __forceinline__ u16 f2h(float f) {
    union { f16 h; u16 u; } x; x.h = (f16)f; return x.u;
}
__device__ __forceinline__ float h2f(u16 u) {
    union { u16 u; f16 h; } x; x.u = u; return (float)x.h;
}
__device__ __forceinline__ void split_fh(float v, u16& h, u16& l) {
    h = f2h(v);
    l = f2h(v - h2f(h));
}

// async global->LDS, 16 B per lane; lds dest must be wave-uniform base (lane L lands at base + L*16)
__device__ __forceinline__ void async_cp16(const u16* gsrc, u16* ldst) {
    __builtin_amdgcn_global_load_lds(
        (const __attribute__((address_space(1))) unsigned int*)gsrc,
        (__attribute__((address_space(3))) unsigned int*)(unsigned int)(unsigned long long)ldst,
        16, 0, 0);
}

// ---------------- elementwise helpers ----------------
// cast fp32*sc -> f16 (and optional lo residual), 4 elems/thread
__global__ void cast_split4(const float* __restrict__ s, u16* __restrict__ h,
                            u16* __restrict__ l, int n4, float sc) {
    int i = blockIdx.x * 256 + threadIdx.x;
    if (i < n4) {
        float4 v = ((const float4*)s)[i];
        v.x *= sc; v.y *= sc; v.z *= sc; v.w *= sc;
        ushort4 hh, ll;
        split_fh(v.x, hh.x, ll.x);
        split_fh(v.y, hh.y, ll.y);
        split_fh(v.z, hh.z, ll.z);
        split_fh(v.w, hh.w, ll.w);
        ((ushort4*)h)[i] = hh;
        if (l) ((ushort4*)l)[i] = ll;
    }
}

// dual-source f16 cast: h[0..n4each) <- s0, h[n4each..2*n4each) <- s1 (one launch for Q+K)
__global__ void cast_dual4(const float* __restrict__ s0, const float* __restrict__ s1,
                           u16* __restrict__ h, int n4each) {
    int i = blockIdx.x * 256 + threadIdx.x;
    if (i < 2 * n4each) {
        const float4* src = (i < n4each) ? (const float4*)s0 : (const float4*)s1;
        int j = (i < n4each) ? i : i - n4each;
        float4 v = src[j];
        ushort4 hh;
        hh.x = f2h(v.x); hh.y = f2h(v.y); hh.z = f2h(v.z); hh.w = f2h(v.w);
        ((ushort4*)h)[i] = hh;
    }
}

// in[R][C] -> out[C][R], LDS-tiled 32x32 (coalesced both sides)
__global__ __launch_bounds__(256)
void transpose_f32(const float* __restrict__ in, float* __restrict__ out, int R, int C) {
    __shared__ float t[32][33];
    const int bx = blockIdx.x * 32;  // C
    const int by = blockIdx.y * 32;  // R
    const int tx = threadIdx.x & 31, ty = threadIdx.x >> 5;
#pragma unroll
    for (int yy = 0; yy < 32; yy += 8)
        t[ty + yy][tx] = in[(long)(by + ty + yy) * C + bx + tx];
    __syncthreads();
#pragma unroll
    for (int yy = 0; yy < 32; yy += 8)
        out[(long)(bx + ty + yy) * R + by + tx] = t[tx][ty + yy];
}

// single-pass softmax over rows of length 2048; input f16 scores (ST16[z][m][n]);
// output P at elem offset m*ldm + z*zoff + n  (parametrized layout:
//   classic [z][m][n]: ldm=cN, zoff=cN*cN;  head-merged [m][z*cN+n]: ldm=G*cN, zoff=cN)
__global__ __launch_bounds__(256)
void softmax_rows(const u16* __restrict__ S16, u16* __restrict__ Ph, long ldm, long zoff) {
    const int bid = blockIdx.x;
    const int z = bid >> 11;          // head index
    const int m = bid & (cN - 1);     // row
    const long rbase = (long)bid * cN;
    const long wbase = (long)m * ldm + (long)z * zoff;
    const int tid = threadIdx.x;
    ushort4 h0 = ((const ushort4*)(S16 + rbase))[tid];
    ushort4 h1 = ((const ushort4*)(S16 + rbase))[tid + 256];
    float v0x = h2f(h0.x), v0y = h2f(h0.y), v0z = h2f(h0.z), v0w = h2f(h0.w);
    float v1x = h2f(h1.x), v1y = h2f(h1.y), v1z = h2f(h1.z), v1w = h2f(h1.w);
    float mx = fmaxf(fmaxf(fmaxf(v0x, v0y), fmaxf(v0z, v0w)),
                     fmaxf(fmaxf(v1x, v1y), fmaxf(v1z, v1w)));
    __shared__ float rm[256], rl[256];
    rm[tid] = mx; __syncthreads();
    for (int w = 128; w > 0; w >>= 1) {
        if (tid < w) rm[tid] = fmaxf(rm[tid], rm[tid + w]);
        __syncthreads();
    }
    mx = rm[0];
    float l = __expf(v0x - mx) + __expf(v0y - mx) + __expf(v0z - mx) + __expf(v0w - mx)
            + __expf(v1x - mx) + __expf(v1y - mx) + __expf(v1z - mx) + __expf(v1w - mx);
    rl[tid] = l; __syncthreads();
    for (int w = 128; w > 0; w >>= 1) {
        if (tid < w) rl[tid] += rl[tid + w];
        __syncthreads();
    }
    const float inv = 1.0f / rl[0];
    ushort4 a, b;
    a.x = f2h(__expf(v0x - mx) * inv);
    a.y = f2h(__expf(v0y - mx) * inv);
    a.z = f2h(__expf(v0z - mx) * inv);
    a.w = f2h(__expf(v0w - mx) * inv);
    b.x = f2h(__expf(v1x - mx) * inv);
    b.y = f2h(__expf(v1y - mx) * inv);
    b.z = f2h(__expf(v1z - mx) * inv);
    b.w = f2h(__expf(v1w - mx) * inv);
    ((ushort4*)(Ph + wbase))[tid] = a;
    ((ushort4*)(Ph + wbase))[tid + 256] = b;
}

// ---- 1-pass f16 GEMM: C[M,N] = alpha*Ah[M,K]*Bh[N,K]^T (+biasN)(relu) ----
// DBUF=3: triple-buffered LDS (48 KB, 3 blocks/CU), counted vmcnt 8/4/0 (T4 depth-3)
// DBUF=2: double-buffered LDS (32 KB, >=4 blocks/CU), vmcnt 4/0 (R4-verified schedule;
//         used for grids sized to fill 4/CU exactly -> no tail round)
// mode: 0 = f16 write, 1 = fp32 write, 3 = fp32 atomicAdd (split-K safe)
// z = (g, s): g batch index (strides bsA/bsB/bsC), s split-K slice (col offset s*K)
// async global_load_lds staging; rotation-swizzled LDS chunks (write-side conflicts
// structural 8-way from global_load_lds lane layout; read-side conflict-free)
template<int DBUF>
__global__ __launch_bounds__(256)
void gemm_f16(const u16* __restrict__ Ah, int lda, long bsA,
              const u16* __restrict__ Bh, int ldb, long bsB,
              float* __restrict__ Cf, u16* __restrict__ Cbh,
              int ldc, long bsC,
              int M, int N, int K, int SK,
              float alpha, int mode, int relu, const float* __restrict__ biasN)
{
    const int g = blockIdx.z / SK;
    const int s = blockIdx.z % SK;
    Ah += (long)g * bsA + (long)s * K;
    Bh += (long)g * bsB + (long)s * K;
    if (s != 0) biasN = nullptr;

    __shared__ __align__(16) u16 Ash[128 * 32];
    __shared__ __align__(16) u16 Bsh[128 * 32];
    __shared__ __align__(16) u16 Ash1[128 * 32];
    __shared__ __align__(16) u16 Bsh1[128 * 32];
    __shared__ __align__(16) u16 Ash2[DBUF == 3 ? 128 * 32 : 8];
    __shared__ __align__(16) u16 Bsh2[DBUF == 3 ? 128 * 32 : 8];

    const int tid  = threadIdx.x;
    const int lane = tid & 63;
    const int wave = tid >> 6;
    const int wm = (wave >> 1) * 64;
    const int wn = (wave & 1) * 64;

    // XCD-aware bijective remap of (by,bx) within each z-slice (m204 formula)
    const int nbx = gridDim.x;
    const int nwg = nbx * (int)gridDim.y;
    int wg = blockIdx.y * nbx + blockIdx.x;
    {
        const int qq = nwg >> 3, rr = nwg & 7;
        const int xcd = wg & 7, lid = wg >> 3;
        wg = (xcd < rr ? xcd * (qq + 1) : rr * (qq + 1) + (xcd - rr) * qq) + lid;
    }
    const int m0 = (wg / nbx) * 128;
    const int n0 = (wg % nbx) * 128;

    // staging lane-statics: chunk c covers rows c*16..+15; lane L -> row c*16+L/4,
    // LDS slot L%4; slot s holds global col-group (s - (row>>2)) & 3  [rotation swizzle]
    const int srow = lane >> 2;                               // 0..15
    const int scol = ((((lane & 3) - (srow >> 2)) & 3) * 8);  // swizzled source col
    // fragment lane-statics: global col-group q lives at slot (q + (r>>2)) & 3
    const int q = lane >> 4;
    const int r = lane & 15;
    const int fcol = (((q + (r >> 2)) & 3) * 8);              // swizzled read col

    f32x4 acc[4][4];
#pragma unroll
    for (int i = 0; i < 4; ++i)
#pragma unroll
        for (int j = 0; j < 4; ++j)
            acc[i][j] = f32x4{0.f, 0.f, 0.f, 0.f};

    auto stage = [&](u16* SA, u16* SB, int k0) {
#pragma unroll
        for (int p = 0; p < 2; ++p) {
            const int c = p * 4 + wave;
            const int grow = c * 16 + srow;
            async_cp16(Ah + (long)(m0 + grow) * lda + k0 + scol, SA + c * 512);
            async_cp16(Bh + (long)(n0 + grow) * ldb + k0 + scol, SB + c * 512);
        }
    };
    auto compute = [&](const u16* SA, const u16* SB) {
        fh8 af[4], bf[4];
#pragma unroll
        for (int i = 0; i < 4; ++i) af[i] = *(const fh8*)(SA + (wm + i * 16 + r) * 32 + fcol);
#pragma unroll
        for (int j = 0; j < 4; ++j) bf[j] = *(const fh8*)(SB + (wn + j * 16 + r) * 32 + fcol);
#pragma unroll
        for (int i = 0; i < 4; ++i)
#pragma unroll
            for (int j = 0; j < 4; ++j)
                acc[i][j] = __builtin_amdgcn_mfma_f32_16x16x32_f16(af[i], bf[j], acc[i][j], 0, 0, 0);
    };

    if constexpr (DBUF == 3) {
        // ---- depth-3 pipeline: prefetch tile t+2 while computing tile t ----
        const int nt = K >> 5;  // K/32 (>=4 at all call sites)
        auto step = [&](const u16* CA, const u16* CB, u16* PA, u16* PB, int pk) {
            if (pk < nt) {
                stage(PA, PB, pk * 32);
                asm volatile("s_waitcnt vmcnt(8)" ::: "memory");   // 2 stages remain in flight
            } else if (pk - 1 < nt) {
                asm volatile("s_waitcnt vmcnt(4)" ::: "memory");   // 1 stage remains in flight
            } else {
                asm volatile("s_waitcnt vmcnt(0)" ::: "memory");   // drain (last tile)
            }
            __builtin_amdgcn_s_barrier();
            compute(CA, CB);
            __builtin_amdgcn_s_barrier();
        };

        stage(Ash,  Bsh,  0);
        stage(Ash1, Bsh1, 32);
        int t = 0;
        for (; t + 3 <= nt; t += 3) {
            step(Ash,  Bsh,  Ash2, Bsh2, t + 2);
            step(Ash1, Bsh1, Ash,  Bsh,  t + 3);
            step(Ash2, Bsh2, Ash1, Bsh1, t + 4);
        }
        if (nt - t == 2) {
            step(Ash,  Bsh,  Ash2, Bsh2, t + 2);   // pk==nt -> vmcnt(4)
            step(Ash1, Bsh1, Ash2, Bsh2, t + 3);   // vmcnt(0)
        } else if (nt - t == 1) {
            step(Ash,  Bsh,  Ash2, Bsh2, t + 2);   // vmcnt(0)
        }
    } else {
        // ---- depth-2 pipeline (R4-verified 2-phase); requires K % 64 == 0 ----
        stage(Ash, Bsh, 0);                       // prologue: 4 loads/wave in flight
        for (int k0 = 0; k0 < K; k0 += 64) {
            // phase A: prefetch k0+32 into buf1, compute k0 from buf0
            stage(Ash1, Bsh1, k0 + 32);           // k0+32 < K always (K%64==0)
            asm volatile("s_waitcnt vmcnt(4)" ::: "memory");  // buf0's 4 loads done
            __builtin_amdgcn_s_barrier();
            compute(Ash, Bsh);
            __builtin_amdgcn_s_barrier();
            // phase B: prefetch k0+64 into buf0 (unless last), compute k0+32 from buf1
            if (k0 + 64 < K) {
                stage(Ash, Bsh, k0 + 64);
                asm volatile("s_waitcnt vmcnt(4)" ::: "memory");
            } else {
                asm volatile("s_waitcnt vmcnt(0)" ::: "memory");
            }
            __builtin_amdgcn_s_barrier();
            compute(Ash1, Bsh1);
            __builtin_amdgcn_s_barrier();
        }
    }

    // C/D layout: col=lane&15, row=(lane>>4)*4+t  [verified m89/m91]
#pragma unroll
    for (int i = 0; i < 4; ++i) {
#pragma unroll
        for (int j = 0; j < 4; ++j) {
            const int col = n0 + wn + j * 16 + r;
#pragma unroll
            for (int t = 0; t < 4; ++t) {
                const int row = m0 + wm + i * 16 + q * 4 + t;
                float v = acc[i][j][t] * alpha;
                if (biasN) v += biasN[col];
                if (relu)  v = fmaxf(v, 0.f);
                const long idx = (long)g * bsC + (long)row * ldc + col;
                if (mode == 0)      Cbh[idx] = f2h(v);
                else if (mode == 1) Cf[idx] = v;
                else                unsafeAtomicAdd(&Cf[idx], v);
            }
        }
    }
}

// ---------------- host ----------------
static inline void launch_gemm(hipStream_t st, int dbuf,
                               const u16* Ah, int lda, long bsA,
                               const u16* Bh, int ldb, long bsB,
                               float* Cf, u16* Cbh, int ldc, long bsC,
                               int M, int N, int K, int Gz, int SK,
                               float alpha, int mode, int relu, const float* biasN)
{
    dim3 grid(N / 128, M / 128, Gz * SK), block(256);
    if (dbuf == 2)
        gemm_f16<2><<<grid, block, 0, st>>>(Ah, lda, bsA, Bh, ldb, bsB,
                                            Cf, Cbh, ldc, bsC,
                                            M, N, K, SK, alpha, mode, relu, biasN);
    else
        gemm_f16<3><<<grid, block, 0, st>>>(Ah, lda, bsA, Bh, ldb, bsB,
                                            Cf, Cbh, ldc, bsC,
                                            M, N, K, SK, alpha, mode, relu, biasN);
}

static inline void launch_cast(hipStream_t st, const float* s, u16* h, u16* l, long n,
                               float sc = 1.0f) {
    int n4 = (int)(n / 4);
    cast_split4<<<dim3((n4 + 255) / 256), dim3(256), 0, st>>>(s, h, l, n4, sc);
}

extern "C" void kernel_launch(void* const* d_in, const int* in_sizes, int n_in,
                              void* d_out, int out_size, void* d_ws, size_t ws_size,
                              hipStream_t stream)
{
    const float* Xin = (const float*)d_in[0];
    const float* Qw  = (const float*)d_in[1];
    const float* Kw  = (const float*)d_in[2];
    const float* Vw  = (const float*)d_in[3];
    const float* W1w = (const float*)d_in[4];
    const float* b1w = (const float*)d_in[5];
    const float* W2w = (const float*)d_in[6];
    const float* b2w = (const float*)d_in[7];
    float* Xout = (float*)d_out;

    // ---- adaptive head-group size from ws_size ----
    int G = 1;
    if      (ws_size >= 402653184ull + 1048576) G = 8;
    else if (ws_size >= 218103808ull + 1048576) G = 4;
    else if (ws_size >= 125829120ull + 1048576) G = 2;

    // ---- workspace carve (identical layout; lo-arrays retained as padding) ----
    char* base = (char*)d_ws;
    size_t off = 0;
    auto carve = [&](size_t bytes) {
        char* p = base + off; off = (off + bytes + 255) & ~(size_t)255; return p;
    };
    float* Xt     = (float*)carve((size_t)cN * cD * 4);   // running X^T [N,D] fp32
    u16*   XbT_h  = (u16*)carve((size_t)cN * cD * 2);
    u16*   XbT_l  = (u16*)carve((size_t)cN * cD * 2);     // unused
    // R1: QKXT' [2][N][D] f16 hi  |  FFN: W1 hi (alias)
    u16*   QKXT_h = (u16*)carve((size_t)2 * cN * cD * 2);
    u16*   QKXT_l = (u16*)carve((size_t)2 * cN * cD * 2); // unused
    u16*   W1_h   = QKXT_h;  // alias (disjoint live ranges)
    (void)XbT_l; (void)QKXT_l;
    // R2
    const size_t r2 = off;
    u16*   ST16 = (u16*)carve((size_t)G * cN * cN * 4);   // f16 scores [z][m][n] (uses half)
    u16*   P_h  = (u16*)carve((size_t)G * cN * cN * 2);   // G==8: [m][z*cN+n]; else [z][m][n]
    u16*   P_l  = (u16*)carve((size_t)G * cN * cN * 2);   // unused
    u16*   Vb_h = (u16*)carve((size_t)G * cD * cD * 2);
    u16*   Vb_l = (u16*)carve((size_t)G * cD * cD * 2);   // unused
    u16*   VX_h = (u16*)carve((size_t)G * cD * cN * 2);   // G==8: [e][z*cN+n]; else [z][e][n]
    u16*   VX_l = (u16*)carve((size_t)G * cD * cN * 2);   // unused
    (void)P_l; (void)Vb_l; (void)VX_l;
    // aliases into R2 front: QK weight casts (dead before group loop starts)
    off = r2;
    u16*   QKb_h = (u16*)carve((size_t)2 * cH * cDK * cD * 2);
    u16*   QKb_l = (u16*)carve((size_t)2 * cH * cDK * cD * 2);  // unused
    (void)QKb_l;
    // aliases into R2: FFN scratch (attention scratch dead by then)
    off = r2;
    u16*   H1_h = (u16*)carve((size_t)cN * cDFF * 2);
    u16*   H1_l = (u16*)carve((size_t)cN * cDFF * 2);     // unused
    u16*   W2_h = (u16*)carve((size_t)cD * cDFF * 2);
    (void)H1_l;

    const u16* QXT_h = QKXT_h;                    // slice 0
    const u16* KXT_h = QKXT_h + (size_t)cN * cD;  // slice 1

    // ---- init: Xt = Xin^T ----
    transpose_f32<<<dim3(cN / 32, cD / 32), dim3(256), 0, stream>>>(Xin, Xt, cD, cN);

    const int SKy = (G >= 4) ? 1 : (G == 2 ? 2 : 4);  // Y GEMM split-K (classic path)

    for (int l = 0; l < cL; ++l) {
        // X^T cast, f16 hi only
        launch_cast(stream, Xt, XbT_h, nullptr, (long)cN * cD);

        // Q,K weights -> contiguous [2][H*DK][D] f16 hi (single dual-source launch)
        const long nQK = (long)cH * cDK * cD;  // 1048576
        {
            int n4each = (int)(nQK / 4);
            cast_dual4<<<dim3((2 * n4each + 255) / 256), dim3(256), 0, stream>>>(
                Qw + (long)l * nQK, Kw + (long)l * nQK, QKb_h, n4each);
        }

        // QKXT'[z][n][h*128+k] = sum_d X[d,n] {Q,K}[h,k,d]  (256 blocks -> depth-3)
        launch_gemm(stream, 3, XbT_h, cD, 0,
                    QKb_h, cD, nQK,
                    nullptr, QKXT_h, cD, (long)cN * cD,
                    cN, cD, cD, 2, 1, 1.f, 0, 0, nullptr);

        for (int g0 = 0; g0 < cH; g0 += G) {
            // ST16[z][m][n] = LAM * sum_k KX[k,m] QX[k,n]
            // (2048 blocks -> depth-2: 32 KB LDS, 4/CU, 2 even rounds)
            launch_gemm(stream, 2, KXT_h + (long)g0 * cDK, cD, cDK,
                        QXT_h + (long)g0 * cDK, cD, cDK,
                        nullptr, ST16, cN, (long)cN * cN,
                        cN, cN, cDK, G, 1, LAM_, 0, 0, nullptr);
            // softmax: classic layout for G<8, head-merged for G==8
            if (G == 8)
                softmax_rows<<<dim3(G * cN), dim3(256), 0, stream>>>(ST16, P_h,
                                                                     (long)G * cN, (long)cN);
            else
                softmax_rows<<<dim3(G * cN), dim3(256), 0, stream>>>(ST16, P_h,
                                                                     (long)cN, (long)cN * cN);

            // V weights (1-pass f16)
            const long nV = (long)cD * cD;
            launch_cast(stream, Vw + ((long)l * cH + g0) * nV, Vb_h, nullptr, (long)G * nV);
            if (G == 8) {
                // VX[e][z*cN+n] = sum_d V[e,d] X[d,n]
                // (1024 blocks -> depth-2: one fully-resident round at 4/CU)
                launch_gemm(stream, 2, Vb_h, cD, nV,
                            XbT_h, cD, 0,
                            nullptr, VX_h, G * cN, (long)cN,
                            cD, cN, cD, G, 1, 1.f, 0, 0, nullptr);
                // Xt[m][e] += sum_{gn} P[m,gn] VX[e,gn]
                // (merged K=16384, SK=8 -> 1024 blocks, depth-2: one resident round at 4/CU;
                //  occupancy-vs-delivery discriminating experiment for the Y floor)
                launch_gemm(stream, 2, P_h, G * cN, 0,
                            VX_h, G * cN, 0,
                            Xt, nullptr, cD, 0,
                            cN, cD, G * cN / 8, 1, 8, 1.f, 3, 0, nullptr);
            } else {
                // classic per-head batched path
                launch_gemm(stream, 3, Vb_h, cD, nV,
                            XbT_h, cD, 0,
                            nullptr, VX_h, cN, (long)cD * cN,
                            cD, cN, cD, G, 1, 1.f, 0, 0, nullptr);
                launch_gemm(stream, 3, P_h, cN, (long)cN * cN,
                            VX_h, cN, (long)cD * cN,
                            Xt, nullptr, cD, 0,
                            cN, cD, cN / SKy, G, SKy, 1.f, 3, 0, nullptr);
            }
        }

        // FFN (post-attention X): all 1-pass f16
        launch_cast(stream, Xt, XbT_h, nullptr, (long)cN * cD);
        const long nW = (long)cDFF * cD;  // 4194304
        launch_cast(stream, W1w + (long)l * nW, W1_h, nullptr, nW);
        // H1[m][f] = relu(sum_d X[d,m] W1[f,d] + b1[f])  (512 blocks -> depth-3, 2/CU even)
        launch_gemm(stream, 3, XbT_h, cD, 0,
                    W1_h, cD, 0,
                    nullptr, H1_h, cDFF, 0,
                    cN, cDFF, cD, 1, 1, 1.f, 0, 1, b1w + (long)l * cDFF);
        launch_cast(stream, W2w + (long)l * nW, W2_h, nullptr, nW);
        // Xt[m][e] += sum_f H1[m,f] W2[e,f] + b2[e]
        // (SK=8 -> 1024 blocks, depth-2: one resident round at 4/CU; bias on s==0 only)
        launch_gemm(stream, 2, H1_h, cDFF, 0,
                    W2_h, cDFF, 0,
                    Xt, nullptr, cD, 0,
                    cN, cD, cDFF / 8, 1, 8, 1.f, 3, 0, b2w + (long)l * cD);
    }

    // out[d][n] = Xt[n][d]
    transpose_f32<<<dim3(cD / 32, cN / 32), dim3(256), 0, stream>>>(Xt, Xout, cN, cD);

    (void)in_sizes; (void)n_in; (void)out_size;
}

// Round 13
// 1664.893 us; speedup vs baseline: 1.0401x; 1.0401x over previous
//
#include <hip/hip_runtime.h>

typedef unsigned short u16;
typedef _Float16 f16;
typedef _Float16 fh8 __attribute__((ext_vector_type(8)));
typedef float f32x4 __attribute__((ext_vector_type(4)));

#define cD   1024
#define cN   2048
#define cH   8
#define cDK  128
#define cDFF 4096
#define cL   4
#define LAM_ 0.08838834764831845f  /* 1/sqrt(128) */

__device__ __forceinline__ u16 f2h(float f) {
    union { f16 h; u16 u; } x; x.h = (f16)f; return x.u;
}
__device__ __forceinline__ float h2f(u16 u) {
    union { u16 u; f16 h; } x; x.u = u; return (float)x.h;
}
__device__ __forceinline__ void split_fh(float v, u16& h, u16& l) {
    h = f2h(v);
    l = f2h(v - h2f(h));
}

// async global->LDS, 16 B per lane; lds dest must be wave-uniform base (lane L lands at base + L*16)
__device__ __forceinline__ void async_cp16(const u16* gsrc, u16* ldst) {
    __builtin_amdgcn_global_load_lds(
        (const __attribute__((address_space(1))) unsigned int*)gsrc,
        (__attribute__((address_space(3))) unsigned int*)(unsigned int)(unsigned long long)ldst,
        16, 0, 0);
}

// ---------------- elementwise helpers ----------------
// cast fp32*sc -> f16 (and optional lo residual), 4 elems/thread
__global__ void cast_split4(const float* __restrict__ s, u16* __restrict__ h,
                            u16* __restrict__ l, int n4, float sc) {
    int i = blockIdx.x * 256 + threadIdx.x;
    if (i < n4) {
        float4 v = ((const float4*)s)[i];
        v.x *= sc; v.y *= sc; v.z *= sc; v.w *= sc;
        ushort4 hh, ll;
        split_fh(v.x, hh.x, ll.x);
        split_fh(v.y, hh.y, ll.y);
        split_fh(v.z, hh.z, ll.z);
        split_fh(v.w, hh.w, ll.w);
        ((ushort4*)h)[i] = hh;
        if (l) ((ushort4*)l)[i] = ll;
    }
}

// dual-source f16 cast: h[0..n4each) <- s0, h[n4each..2*n4each) <- s1 (one launch for Q+K)
__global__ void cast_dual4(const float* __restrict__ s0, const float* __restrict__ s1,
                           u16* __restrict__ h, int n4each) {
    int i = blockIdx.x * 256 + threadIdx.x;
    if (i < 2 * n4each) {
        const float4* src = (i < n4each) ? (const float4*)s0 : (const float4*)s1;
        int j = (i < n4each) ? i : i - n4each;
        float4 v = src[j];
        ushort4 hh;
        hh.x = f2h(v.x); hh.y = f2h(v.y); hh.z = f2h(v.z); hh.w = f2h(v.w);
        ((ushort4*)h)[i] = hh;
    }
}

// in[R][C] -> out[C][R], LDS-tiled 32x32 (coalesced both sides)
__global__ __launch_bounds__(256)
void transpose_f32(const float* __restrict__ in, float* __restrict__ out, int R, int C) {
    __shared__ float t[32][33];
    const int bx = blockIdx.x * 32;  // C
    const int by = blockIdx.y * 32;  // R
    const int tx = threadIdx.x & 31, ty = threadIdx.x >> 5;
#pragma unroll
    for (int yy = 0; yy < 32; yy += 8)
        t[ty + yy][tx] = in[(long)(by + ty + yy) * C + bx + tx];
    __syncthreads();
#pragma unroll
    for (int yy = 0; yy < 32; yy += 8)
        out[(long)(bx + ty + yy) * R + by + tx] = t[tx][ty + yy];
}

// single-pass softmax over rows of length 2048; input f16 scores (ST16[z][m][n]);
// output P at elem offset m*ldm + z*zoff + n  (parametrized layout:
//   classic [z][m][n]: ldm=cN, zoff=cN*cN;  head-merged [m][z*cN+n]: ldm=G*cN, zoff=cN)
__global__ __launch_bounds__(256)
void softmax_rows(const u16* __restrict__ S16, u16* __restrict__ Ph, long ldm, long zoff) {
    const int bid = blockIdx.x;
    const int z = bid >> 11;          // head index
    const int m = bid & (cN - 1);     // row
    const long rbase = (long)bid * cN;
    const long wbase = (long)m * ldm + (long)z * zoff;
    const int tid = threadIdx.x;
    ushort4 h0 = ((const ushort4*)(S16 + rbase))[tid];
    ushort4 h1 = ((const ushort4*)(S16 + rbase))[tid + 256];
    float v0x = h2f(h0.x), v0y = h2f(h0.y), v0z = h2f(h0.z), v0w = h2f(h0.w);
    float v1x = h2f(h1.x), v1y = h2f(h1.y), v1z = h2f(h1.z), v1w = h2f(h1.w);
    float mx = fmaxf(fmaxf(fmaxf(v0x, v0y), fmaxf(v0z, v0w)),
                     fmaxf(fmaxf(v1x, v1y), fmaxf(v1z, v1w)));
    __shared__ float rm[256], rl[256];
    rm[tid] = mx; __syncthreads();
    for (int w = 128; w > 0; w >>= 1) {
        if (tid < w) rm[tid] = fmaxf(rm[tid], rm[tid + w]);
        __syncthreads();
    }
    mx = rm[0];
    float l = __expf(v0x - mx) + __expf(v0y - mx) + __expf(v0z - mx) + __expf(v0w - mx)
            + __expf(v1x - mx) + __expf(v1y - mx) + __expf(v1z - mx) + __expf(v1w - mx);
    rl[tid] = l; __syncthreads();
    for (int w = 128; w > 0; w >>= 1) {
        if (tid < w) rl[tid] += rl[tid + w];
        __syncthreads();
    }
    const float inv = 1.0f / rl[0];
    ushort4 a, b;
    a.x = f2h(__expf(v0x - mx) * inv);
    a.y = f2h(__expf(v0y - mx) * inv);
    a.z = f2h(__expf(v0z - mx) * inv);
    a.w = f2h(__expf(v0w - mx) * inv);
    b.x = f2h(__expf(v1x - mx) * inv);
    b.y = f2h(__expf(v1y - mx) * inv);
    b.z = f2h(__expf(v1z - mx) * inv);
    b.w = f2h(__expf(v1w - mx) * inv);
    ((ushort4*)(Ph + wbase))[tid] = a;
    ((ushort4*)(Ph + wbase))[tid + 256] = b;
}

// ---- 1-pass f16 GEMM: C[M,N] = alpha*Ah[M,K]*Bh[N,K]^T (+biasN)(relu) ----
// DBUF=3: triple-buffered LDS (48 KB, 3 blocks/CU), counted vmcnt 8/4/0 (T4 depth-3)
// DBUF=2: double-buffered LDS (32 KB, >=4 blocks/CU), vmcnt 4/0 (R4-verified schedule;
//         for large grids where depth-3's 3/CU capacity would leave a tail round)
// mode: 0 = f16 write, 1 = fp32 write, 3 = fp32 atomicAdd (split-K safe)
// z = (g, s): g batch index (strides bsA/bsB/bsC), s split-K slice (col offset s*K)
// async global_load_lds staging; rotation-swizzled LDS chunks (write-side conflicts
// structural 8-way from global_load_lds lane layout; read-side conflict-free)
template<int DBUF>
__global__ __launch_bounds__(256)
void gemm_f16(const u16* __restrict__ Ah, int lda, long bsA,
              const u16* __restrict__ Bh, int ldb, long bsB,
              float* __restrict__ Cf, u16* __restrict__ Cbh,
              int ldc, long bsC,
              int M, int N, int K, int SK,
              float alpha, int mode, int relu, const float* __restrict__ biasN)
{
    const int g = blockIdx.z / SK;
    const int s = blockIdx.z % SK;
    Ah += (long)g * bsA + (long)s * K;
    Bh += (long)g * bsB + (long)s * K;
    if (s != 0) biasN = nullptr;

    __shared__ __align__(16) u16 Ash[128 * 32];
    __shared__ __align__(16) u16 Bsh[128 * 32];
    __shared__ __align__(16) u16 Ash1[128 * 32];
    __shared__ __align__(16) u16 Bsh1[128 * 32];
    __shared__ __align__(16) u16 Ash2[DBUF == 3 ? 128 * 32 : 8];
    __shared__ __align__(16) u16 Bsh2[DBUF == 3 ? 128 * 32 : 8];

    const int tid  = threadIdx.x;
    const int lane = tid & 63;
    const int wave = tid >> 6;
    const int wm = (wave >> 1) * 64;
    const int wn = (wave & 1) * 64;

    // XCD-aware bijective remap of (by,bx) within each z-slice (m204 formula)
    const int nbx = gridDim.x;
    const int nwg = nbx * (int)gridDim.y;
    int wg = blockIdx.y * nbx + blockIdx.x;
    {
        const int qq = nwg >> 3, rr = nwg & 7;
        const int xcd = wg & 7, lid = wg >> 3;
        wg = (xcd < rr ? xcd * (qq + 1) : rr * (qq + 1) + (xcd - rr) * qq) + lid;
    }
    const int m0 = (wg / nbx) * 128;
    const int n0 = (wg % nbx) * 128;

    // staging lane-statics: chunk c covers rows c*16..+15; lane L -> row c*16+L/4,
    // LDS slot L%4; slot s holds global col-group (s - (row>>2)) & 3  [rotation swizzle]
    const int srow = lane >> 2;                               // 0..15
    const int scol = ((((lane & 3) - (srow >> 2)) & 3) * 8);  // swizzled source col
    // fragment lane-statics: global col-group q lives at slot (q + (r>>2)) & 3
    const int q = lane >> 4;
    const int r = lane & 15;
    const int fcol = (((q + (r >> 2)) & 3) * 8);              // swizzled read col

    f32x4 acc[4][4];
#pragma unroll
    for (int i = 0; i < 4; ++i)
#pragma unroll
        for (int j = 0; j < 4; ++j)
            acc[i][j] = f32x4{0.f, 0.f, 0.f, 0.f};

    auto stage = [&](u16* SA, u16* SB, int k0) {
#pragma unroll
        for (int p = 0; p < 2; ++p) {
            const int c = p * 4 + wave;
            const int grow = c * 16 + srow;
            async_cp16(Ah + (long)(m0 + grow) * lda + k0 + scol, SA + c * 512);
            async_cp16(Bh + (long)(n0 + grow) * ldb + k0 + scol, SB + c * 512);
        }
    };
    auto compute = [&](const u16* SA, const u16* SB) {
        fh8 af[4], bf[4];
#pragma unroll
        for (int i = 0; i < 4; ++i) af[i] = *(const fh8*)(SA + (wm + i * 16 + r) * 32 + fcol);
#pragma unroll
        for (int j = 0; j < 4; ++j) bf[j] = *(const fh8*)(SB + (wn + j * 16 + r) * 32 + fcol);
#pragma unroll
        for (int i = 0; i < 4; ++i)
#pragma unroll
            for (int j = 0; j < 4; ++j)
                acc[i][j] = __builtin_amdgcn_mfma_f32_16x16x32_f16(af[i], bf[j], acc[i][j], 0, 0, 0);
    };

    if constexpr (DBUF == 3) {
        // ---- depth-3 pipeline: prefetch tile t+2 while computing tile t ----
        const int nt = K >> 5;  // K/32 (>=4 at all call sites)
        auto step = [&](const u16* CA, const u16* CB, u16* PA, u16* PB, int pk) {
            if (pk < nt) {
                stage(PA, PB, pk * 32);
                asm volatile("s_waitcnt vmcnt(8)" ::: "memory");   // 2 stages remain in flight
            } else if (pk - 1 < nt) {
                asm volatile("s_waitcnt vmcnt(4)" ::: "memory");   // 1 stage remains in flight
            } else {
                asm volatile("s_waitcnt vmcnt(0)" ::: "memory");   // drain (last tile)
            }
            __builtin_amdgcn_s_barrier();
            compute(CA, CB);
            __builtin_amdgcn_s_barrier();
        };

        stage(Ash,  Bsh,  0);
        stage(Ash1, Bsh1, 32);
        int t = 0;
        for (; t + 3 <= nt; t += 3) {
            step(Ash,  Bsh,  Ash2, Bsh2, t + 2);
            step(Ash1, Bsh1, Ash,  Bsh,  t + 3);
            step(Ash2, Bsh2, Ash1, Bsh1, t + 4);
        }
        if (nt - t == 2) {
            step(Ash,  Bsh,  Ash2, Bsh2, t + 2);   // pk==nt -> vmcnt(4)
            step(Ash1, Bsh1, Ash2, Bsh2, t + 3);   // vmcnt(0)
        } else if (nt - t == 1) {
            step(Ash,  Bsh,  Ash2, Bsh2, t + 2);   // vmcnt(0)
        }
    } else {
        // ---- depth-2 pipeline (R4-verified 2-phase); requires K % 64 == 0 ----
        stage(Ash, Bsh, 0);                       // prologue: 4 loads/wave in flight
        for (int k0 = 0; k0 < K; k0 += 64) {
            // phase A: prefetch k0+32 into buf1, compute k0 from buf0
            stage(Ash1, Bsh1, k0 + 32);           // k0+32 < K always (K%64==0)
            asm volatile("s_waitcnt vmcnt(4)" ::: "memory");  // buf0's 4 loads done
            __builtin_amdgcn_s_barrier();
            compute(Ash, Bsh);
            __builtin_amdgcn_s_barrier();
            // phase B: prefetch k0+64 into buf0 (unless last), compute k0+32 from buf1
            if (k0 + 64 < K) {
                stage(Ash, Bsh, k0 + 64);
                asm volatile("s_waitcnt vmcnt(4)" ::: "memory");
            } else {
                asm volatile("s_waitcnt vmcnt(0)" ::: "memory");
            }
            __builtin_amdgcn_s_barrier();
            compute(Ash1, Bsh1);
            __builtin_amdgcn_s_barrier();
        }
    }

    // C/D layout: col=lane&15, row=(lane>>4)*4+t  [verified m89/m91]
#pragma unroll
    for (int i = 0; i < 4; ++i) {
#pragma unroll
        for (int j = 0; j < 4; ++j) {
            const int col = n0 + wn + j * 16 + r;
#pragma unroll
            for (int t = 0; t < 4; ++t) {
                const int row = m0 + wm + i * 16 + q * 4 + t;
                float v = acc[i][j][t] * alpha;
                if (biasN) v += biasN[col];
                if (relu)  v = fmaxf(v, 0.f);
                const long idx = (long)g * bsC + (long)row * ldc + col;
                if (mode == 0)      Cbh[idx] = f2h(v);
                else if (mode == 1) Cf[idx] = v;
                else                unsafeAtomicAdd(&Cf[idx], v);
            }
        }
    }
}

// ---------------- host ----------------
static inline void launch_gemm(hipStream_t st, int dbuf,
                               const u16* Ah, int lda, long bsA,
                               const u16* Bh, int ldb, long bsB,
                               float* Cf, u16* Cbh, int ldc, long bsC,
                               int M, int N, int K, int Gz, int SK,
                               float alpha, int mode, int relu, const float* biasN)
{
    dim3 grid(N / 128, M / 128, Gz * SK), block(256);
    if (dbuf == 2)
        gemm_f16<2><<<grid, block, 0, st>>>(Ah, lda, bsA, Bh, ldb, bsB,
                                            Cf, Cbh, ldc, bsC,
                                            M, N, K, SK, alpha, mode, relu, biasN);
    else
        gemm_f16<3><<<grid, block, 0, st>>>(Ah, lda, bsA, Bh, ldb, bsB,
                                            Cf, Cbh, ldc, bsC,
                                            M, N, K, SK, alpha, mode, relu, biasN);
}

static inline void launch_cast(hipStream_t st, const float* s, u16* h, u16* l, long n,
                               float sc = 1.0f) {
    int n4 = (int)(n / 4);
    cast_split4<<<dim3((n4 + 255) / 256), dim3(256), 0, st>>>(s, h, l, n4, sc);
}

extern "C" void kernel_launch(void* const* d_in, const int* in_sizes, int n_in,
                              void* d_out, int out_size, void* d_ws, size_t ws_size,
                              hipStream_t stream)
{
    const float* Xin = (const float*)d_in[0];
    const float* Qw  = (const float*)d_in[1];
    const float* Kw  = (const float*)d_in[2];
    const float* Vw  = (const float*)d_in[3];
    const float* W1w = (const float*)d_in[4];
    const float* b1w = (const float*)d_in[5];
    const float* W2w = (const float*)d_in[6];
    const float* b2w = (const float*)d_in[7];
    float* Xout = (float*)d_out;

    // ---- adaptive head-group size from ws_size ----
    int G = 1;
    if      (ws_size >= 402653184ull + 1048576) G = 8;
    else if (ws_size >= 218103808ull + 1048576) G = 4;
    else if (ws_size >= 125829120ull + 1048576) G = 2;

    // ---- workspace carve (identical layout; lo-arrays retained as padding) ----
    char* base = (char*)d_ws;
    size_t off = 0;
    auto carve = [&](size_t bytes) {
        char* p = base + off; off = (off + bytes + 255) & ~(size_t)255; return p;
    };
    float* Xt     = (float*)carve((size_t)cN * cD * 4);   // running X^T [N,D] fp32
    u16*   XbT_h  = (u16*)carve((size_t)cN * cD * 2);
    u16*   XbT_l  = (u16*)carve((size_t)cN * cD * 2);     // unused
    // R1: QKXT' [2][N][D] f16 hi  |  FFN: W1 hi (alias)
    u16*   QKXT_h = (u16*)carve((size_t)2 * cN * cD * 2);
    u16*   QKXT_l = (u16*)carve((size_t)2 * cN * cD * 2); // unused
    u16*   W1_h   = QKXT_h;  // alias (disjoint live ranges)
    (void)XbT_l; (void)QKXT_l;
    // R2
    const size_t r2 = off;
    u16*   ST16 = (u16*)carve((size_t)G * cN * cN * 4);   // f16 scores [z][m][n] (uses half)
    u16*   P_h  = (u16*)carve((size_t)G * cN * cN * 2);   // G==8: [m][z*cN+n]; else [z][m][n]
    u16*   P_l  = (u16*)carve((size_t)G * cN * cN * 2);   // unused
    u16*   Vb_h = (u16*)carve((size_t)G * cD * cD * 2);
    u16*   Vb_l = (u16*)carve((size_t)G * cD * cD * 2);   // unused
    u16*   VX_h = (u16*)carve((size_t)G * cD * cN * 2);   // G==8: [e][z*cN+n]; else [z][e][n]
    u16*   VX_l = (u16*)carve((size_t)G * cD * cN * 2);   // unused
    (void)P_l; (void)Vb_l; (void)VX_l;
    // aliases into R2 front: QK weight casts (dead before group loop starts)
    off = r2;
    u16*   QKb_h = (u16*)carve((size_t)2 * cH * cDK * cD * 2);
    u16*   QKb_l = (u16*)carve((size_t)2 * cH * cDK * cD * 2);  // unused
    (void)QKb_l;
    // aliases into R2: FFN scratch (attention scratch dead by then)
    off = r2;
    u16*   H1_h = (u16*)carve((size_t)cN * cDFF * 2);
    u16*   H1_l = (u16*)carve((size_t)cN * cDFF * 2);     // unused
    u16*   W2_h = (u16*)carve((size_t)cD * cDFF * 2);
    (void)H1_l;

    const u16* QXT_h = QKXT_h;                    // slice 0
    const u16* KXT_h = QKXT_h + (size_t)cN * cD;  // slice 1

    // ---- init: Xt = Xin^T ----
    transpose_f32<<<dim3(cN / 32, cD / 32), dim3(256), 0, stream>>>(Xin, Xt, cD, cN);

    const int SKy = (G >= 4) ? 1 : (G == 2 ? 2 : 4);  // Y GEMM split-K (classic path)

    for (int l = 0; l < cL; ++l) {
        // X^T cast, f16 hi only
        launch_cast(stream, Xt, XbT_h, nullptr, (long)cN * cD);

        // Q,K weights -> contiguous [2][H*DK][D] f16 hi (single dual-source launch)
        const long nQK = (long)cH * cDK * cD;  // 1048576
        {
            int n4each = (int)(nQK / 4);
            cast_dual4<<<dim3((2 * n4each + 255) / 256), dim3(256), 0, stream>>>(
                Qw + (long)l * nQK, Kw + (long)l * nQK, QKb_h, n4each);
        }

        // QKXT'[z][n][h*128+k] = sum_d X[d,n] {Q,K}[h,k,d]  (256 blocks -> depth-3)
        launch_gemm(stream, 3, XbT_h, cD, 0,
                    QKb_h, cD, nQK,
                    nullptr, QKXT_h, cD, (long)cN * cD,
                    cN, cD, cD, 2, 1, 1.f, 0, 0, nullptr);

        for (int g0 = 0; g0 < cH; g0 += G) {
            // ST16[z][m][n] = LAM * sum_k KX[k,m] QX[k,n]
            // (2048 blocks -> depth-2: 32 KB LDS, 4/CU, 2 even rounds)
            launch_gemm(stream, 2, KXT_h + (long)g0 * cDK, cD, cDK,
                        QXT_h + (long)g0 * cDK, cD, cDK,
                        nullptr, ST16, cN, (long)cN * cN,
                        cN, cN, cDK, G, 1, LAM_, 0, 0, nullptr);
            // softmax: classic layout for G<8, head-merged for G==8
            if (G == 8)
                softmax_rows<<<dim3(G * cN), dim3(256), 0, stream>>>(ST16, P_h,
                                                                     (long)G * cN, (long)cN);
            else
                softmax_rows<<<dim3(G * cN), dim3(256), 0, stream>>>(ST16, P_h,
                                                                     (long)cN, (long)cN * cN);

            // V weights (1-pass f16)
            const long nV = (long)cD * cD;
            launch_cast(stream, Vw + ((long)l * cH + g0) * nV, Vb_h, nullptr, (long)G * nV);
            if (G == 8) {
                // VX[e][z*cN+n] = sum_d V[e,d] X[d,n]
                // (1024 blocks -> depth-2: one fully-resident round at 4/CU)
                launch_gemm(stream, 2, Vb_h, cD, nV,
                            XbT_h, cD, 0,
                            nullptr, VX_h, G * cN, (long)cN,
                            cD, cN, cD, G, 1, 1.f, 0, 0, nullptr);
                // Xt[m][e] += sum_{gn} P[m,gn] VX[e,gn]
                // (merged K=16384, SK=4 -> 512 blocks, depth-3: R11-proven best —
                //  R12's SK=8/depth-2 experiment regressed 103.5->121 us; delivery-bound)
                launch_gemm(stream, 3, P_h, G * cN, 0,
                            VX_h, G * cN, 0,
                            Xt, nullptr, cD, 0,
                            cN, cD, G * cN / 4, 1, 4, 1.f, 3, 0, nullptr);
            } else {
                // classic per-head batched path
                launch_gemm(stream, 3, Vb_h, cD, nV,
                            XbT_h, cD, 0,
                            nullptr, VX_h, cN, (long)cD * cN,
                            cD, cN, cD, G, 1, 1.f, 0, 0, nullptr);
                launch_gemm(stream, 3, P_h, cN, (long)cN * cN,
                            VX_h, cN, (long)cD * cN,
                            Xt, nullptr, cD, 0,
                            cN, cD, cN / SKy, G, SKy, 1.f, 3, 0, nullptr);
            }
        }

        // FFN (post-attention X): all 1-pass f16
        launch_cast(stream, Xt, XbT_h, nullptr, (long)cN * cD);
        const long nW = (long)cDFF * cD;  // 4194304
        launch_cast(stream, W1w + (long)l * nW, W1_h, nullptr, nW);
        // H1[m][f] = relu(sum_d X[d,m] W1[f,d] + b1[f])  (512 blocks -> depth-3, all resident)
        launch_gemm(stream, 3, XbT_h, cD, 0,
                    W1_h, cD, 0,
                    nullptr, H1_h, cDFF, 0,
                    cN, cDFF, cD, 1, 1, 1.f, 0, 1, b1w + (long)l * cDFF);
        launch_cast(stream, W2w + (long)l * nW, W2_h, nullptr, nW);
        // Xt[m][e] += sum_f H1[m,f] W2[e,f] + b2[e]  (SK=4 -> 512 blocks, depth-3; R11 config)
        launch_gemm(stream, 3, H1_h, cDFF, 0,
                    W2_h, cDFF, 0,
                    Xt, nullptr, cD, 0,
                    cN, cD, cDFF / 4, 1, 4, 1.f, 3, 0, b2w + (long)l * cD);
    }

    // out[d][n] = Xt[n][d]
    transpose_f32<<<dim3(cD / 32, cN / 32), dim3(256), 0, stream>>>(Xt, Xout, cN, cD);

    (void)in_sizes; (void)n_in; (void)out_size;
}